// Round 9
// baseline (1119.703 us; speedup 1.0000x reference)
//
#include <hip/hip_runtime.h>
#include <cstddef>
#include <cstdint>

#define TS 2048   // sequence length S
#define TD 512    // model dim D
#define TH 8      // heads
#define TDH 64    // head dim

typedef float f32x4 __attribute__((ext_vector_type(4)));
typedef short short8v __attribute__((ext_vector_type(8)));

__device__ __forceinline__ unsigned short f2bf(float f) {
  unsigned u = __builtin_bit_cast(unsigned, f);
  u += 0x7fff + ((u >> 16) & 1);          // RNE
  return (unsigned short)(u >> 16);
}
__device__ __forceinline__ float bf2f(unsigned short u) {
  return __builtin_bit_cast(float, (unsigned)u << 16);
}

// ---------------------------------------------------------------------------
// Fused QKV projection: one launch, W selected per blockIdx.y.
// by 0..7 -> Wq (bf16 head-major Qh), 8..15 -> Wk (-> Kh), 16 -> Wv (f32 Vb).
// Body = proven gemm_mfma (64x64 tile, BK=32, 2x2 waves of 32x32).
// ---------------------------------------------------------------------------
__global__ __launch_bounds__(256) void proj_gemm(
    const float* __restrict__ x,
    const float* __restrict__ Wq, const float* __restrict__ bq,
    const float* __restrict__ Wk, const float* __restrict__ bk,
    const float* __restrict__ Wv, const float* __restrict__ bv,
    short* __restrict__ Qh, short* __restrict__ Kh, float* __restrict__ Vb)
{
  __shared__ short As[64][40];
  __shared__ short Bs[64][40];

  const int by = blockIdx.y;
  const float* W; const float* bias; int N; int col0; int outsel;
  if (by < 8)       { W = Wq; bias = bq; N = TD;  col0 = by * 64;       outsel = 0; }
  else if (by < 16) { W = Wk; bias = bk; N = TD;  col0 = (by - 8) * 64; outsel = 1; }
  else              { W = Wv; bias = bv; N = TDH; col0 = 0;             outsel = 2; }

  const int tid  = threadIdx.x;
  const int w    = tid >> 6;
  const int lane = tid & 63;
  const int g    = lane >> 4;
  const int lc16 = lane & 15;
  const int wm   = w >> 1;
  const int wn   = w & 1;
  const int row0 = blockIdx.x * 64;

  const int ar = tid >> 2;
  const int ak = (tid & 3) << 3;
  const int wk = tid >> 3;
  const int wn8 = (tid & 7) << 3;

  f32x4 acc[2][2];
#pragma unroll
  for (int i = 0; i < 2; ++i)
#pragma unroll
    for (int j = 0; j < 2; ++j) acc[i][j] = (f32x4){0.f, 0.f, 0.f, 0.f};

  for (int kt = 0; kt < TD; kt += 32) {
    {
      const float* ap = x + (size_t)(row0 + ar) * TD + kt + ak;
      float4 f0 = *(const float4*)ap;
      float4 f1 = *(const float4*)(ap + 4);
      short8v v;
      v[0] = (short)f2bf(f0.x); v[1] = (short)f2bf(f0.y);
      v[2] = (short)f2bf(f0.z); v[3] = (short)f2bf(f0.w);
      v[4] = (short)f2bf(f1.x); v[5] = (short)f2bf(f1.y);
      v[6] = (short)f2bf(f1.z); v[7] = (short)f2bf(f1.w);
      *(short8v*)&As[ar][ak] = v;
    }
    {
      const float* wp = W + (size_t)(kt + wk) * N + col0 + wn8;
      float4 f0 = *(const float4*)wp;
      float4 f1 = *(const float4*)(wp + 4);
      Bs[wn8 + 0][wk] = (short)f2bf(f0.x);
      Bs[wn8 + 1][wk] = (short)f2bf(f0.y);
      Bs[wn8 + 2][wk] = (short)f2bf(f0.z);
      Bs[wn8 + 3][wk] = (short)f2bf(f0.w);
      Bs[wn8 + 4][wk] = (short)f2bf(f1.x);
      Bs[wn8 + 5][wk] = (short)f2bf(f1.y);
      Bs[wn8 + 6][wk] = (short)f2bf(f1.z);
      Bs[wn8 + 7][wk] = (short)f2bf(f1.w);
    }
    __syncthreads();

    short8v a0 = *(const short8v*)&As[wm * 32 + lc16][g * 8];
    short8v a1 = *(const short8v*)&As[wm * 32 + 16 + lc16][g * 8];
    short8v b0 = *(const short8v*)&Bs[wn * 32 + lc16][g * 8];
    short8v b1 = *(const short8v*)&Bs[wn * 32 + 16 + lc16][g * 8];
    acc[0][0] = __builtin_amdgcn_mfma_f32_16x16x32_bf16(a0, b0, acc[0][0], 0, 0, 0);
    acc[0][1] = __builtin_amdgcn_mfma_f32_16x16x32_bf16(a0, b1, acc[0][1], 0, 0, 0);
    acc[1][0] = __builtin_amdgcn_mfma_f32_16x16x32_bf16(a1, b0, acc[1][0], 0, 0, 0);
    acc[1][1] = __builtin_amdgcn_mfma_f32_16x16x32_bf16(a1, b1, acc[1][1], 0, 0, 0);
    __syncthreads();
  }

  short* Obf = (outsel == 0) ? Qh : Kh;
#pragma unroll
  for (int ni = 0; ni < 2; ++ni) {
    const int ocol = col0 + wn * 32 + ni * 16 + lc16;
    if (ocol >= N) continue;
    const float bb = bias[ocol];
#pragma unroll
    for (int mi = 0; mi < 2; ++mi)
#pragma unroll
      for (int r = 0; r < 4; ++r) {
        const int orow = row0 + wm * 32 + mi * 16 + g * 4 + r;
        const float val = acc[mi][ni][r] + bb;
        if (outsel == 2) {
          Vb[(size_t)orow * TDH + ocol] = val;
        } else {
          const int bI = orow >> 11, s = orow & 2047;
          const int hI = ocol >> 6, dh = ocol & 63;
          Obf[(((size_t)(bI * TH + hI) * TS + s) * TDH) + dh] = (short)f2bf(val);
        }
      }
  }
}

// ---------------------------------------------------------------------------
// Output projection GEMM (proven): x_out = Hd(bf16) @ Wout + bout.
// ---------------------------------------------------------------------------
__global__ __launch_bounds__(256) void gemm_out(
    const short* __restrict__ A, const float* __restrict__ W,
    const float* __restrict__ bias, float* __restrict__ Cf, int N, int Kd)
{
  __shared__ short As[64][40];
  __shared__ short Bs[64][40];

  const int tid  = threadIdx.x;
  const int w    = tid >> 6;
  const int lane = tid & 63;
  const int g    = lane >> 4;
  const int lc16 = lane & 15;
  const int wm   = w >> 1;
  const int wn   = w & 1;
  const int row0 = blockIdx.x * 64;
  const int col0 = blockIdx.y * 64;

  const int ar = tid >> 2;
  const int ak = (tid & 3) << 3;
  const int wk = tid >> 3;
  const int wn8 = (tid & 7) << 3;

  f32x4 acc[2][2];
#pragma unroll
  for (int i = 0; i < 2; ++i)
#pragma unroll
    for (int j = 0; j < 2; ++j) acc[i][j] = (f32x4){0.f, 0.f, 0.f, 0.f};

  for (int kt = 0; kt < Kd; kt += 32) {
    {
      short8v v = *(const short8v*)(A + (size_t)(row0 + ar) * Kd + kt + ak);
      *(short8v*)&As[ar][ak] = v;
    }
    {
      const float* wp = W + (size_t)(kt + wk) * N + col0 + wn8;
      float4 f0 = *(const float4*)wp;
      float4 f1 = *(const float4*)(wp + 4);
      Bs[wn8 + 0][wk] = (short)f2bf(f0.x);
      Bs[wn8 + 1][wk] = (short)f2bf(f0.y);
      Bs[wn8 + 2][wk] = (short)f2bf(f0.z);
      Bs[wn8 + 3][wk] = (short)f2bf(f0.w);
      Bs[wn8 + 4][wk] = (short)f2bf(f1.x);
      Bs[wn8 + 5][wk] = (short)f2bf(f1.y);
      Bs[wn8 + 6][wk] = (short)f2bf(f1.z);
      Bs[wn8 + 7][wk] = (short)f2bf(f1.w);
    }
    __syncthreads();

    short8v a0 = *(const short8v*)&As[wm * 32 + lc16][g * 8];
    short8v a1 = *(const short8v*)&As[wm * 32 + 16 + lc16][g * 8];
    short8v b0 = *(const short8v*)&Bs[wn * 32 + lc16][g * 8];
    short8v b1 = *(const short8v*)&Bs[wn * 32 + 16 + lc16][g * 8];
    acc[0][0] = __builtin_amdgcn_mfma_f32_16x16x32_bf16(a0, b0, acc[0][0], 0, 0, 0);
    acc[0][1] = __builtin_amdgcn_mfma_f32_16x16x32_bf16(a0, b1, acc[0][1], 0, 0, 0);
    acc[1][0] = __builtin_amdgcn_mfma_f32_16x16x32_bf16(a1, b0, acc[1][0], 0, 0, 0);
    acc[1][1] = __builtin_amdgcn_mfma_f32_16x16x32_bf16(a1, b1, acc[1][1], 0, 0, 0);
    __syncthreads();
  }

#pragma unroll
  for (int ni = 0; ni < 2; ++ni) {
    const int ocol = col0 + wn * 32 + ni * 16 + lc16;
    const float bb = bias[ocol];
#pragma unroll
    for (int mi = 0; mi < 2; ++mi)
#pragma unroll
      for (int r = 0; r < 4; ++r) {
        const int orow = row0 + wm * 32 + mi * 16 + g * 4 + r;
        Cf[(size_t)orow * N + ocol] = acc[mi][ni][r] + bb;
      }
  }
}

// ---------------------------------------------------------------------------
// zcand: QK^T in registers (R8 zgemm structure, swapped operands), NO Z store.
// Block = 64q x 256j x one head. Block-row max (256 j) via one LDS exchange;
// admit z > blockmax-1 (superset of global candidates since blockmax<=rowmax)
// into global per-row lists. ~11 cands/block-row expected.
// MFMA(K,Q): D col = q (lane&15), row = j ((lane>>4)*4+reg).
// ---------------------------------------------------------------------------
__global__ __launch_bounds__(256) void zcand(
    const short* __restrict__ Qh, const short* __restrict__ Kh,
    int* __restrict__ cnt, unsigned short* __restrict__ idxL,
    float* __restrict__ valL, int capN)
{
  __shared__ float redW[4][64];

  const int tid  = threadIdx.x;
  const int w    = tid >> 6;
  const int lane = tid & 63;
  const int g    = lane >> 4;
  const int lc16 = lane & 15;
  const int pair = blockIdx.z;
  const int jb   = blockIdx.x * 256 + w * 64;
  const int qb   = blockIdx.y * 64;

  const short* Qp = Qh + (size_t)pair * TS * TDH;
  const short* Kp = Kh + (size_t)pair * TS * TDH;

  short8v bq[4][2];
#pragma unroll
  for (int ct = 0; ct < 4; ++ct) {
    const short* qp = Qp + (size_t)(qb + ct * 16 + lc16) * TDH + g * 8;
    bq[ct][0] = *(const short8v*)qp;
    bq[ct][1] = *(const short8v*)(qp + 32);
  }

  f32x4 acc[4][4];
#pragma unroll
  for (int rt = 0; rt < 4; ++rt)
#pragma unroll
    for (int ct = 0; ct < 4; ++ct) acc[rt][ct] = (f32x4){0.f, 0.f, 0.f, 0.f};

#pragma unroll
  for (int rt = 0; rt < 4; ++rt) {
    const short* kp = Kp + (size_t)(jb + rt * 16 + lc16) * TDH + g * 8;
    short8v ak0 = *(const short8v*)kp;
    short8v ak1 = *(const short8v*)(kp + 32);
#pragma unroll
    for (int ct = 0; ct < 4; ++ct) {
      acc[rt][ct] = __builtin_amdgcn_mfma_f32_16x16x32_bf16(ak0, bq[ct][0], acc[rt][ct], 0, 0, 0);
      acc[rt][ct] = __builtin_amdgcn_mfma_f32_16x16x32_bf16(ak1, bq[ct][1], acc[rt][ct], 0, 0, 0);
    }
  }

  // per-q max over this wave's 64 j
  float m[4];
#pragma unroll
  for (int ct = 0; ct < 4; ++ct) {
    float mm = acc[0][ct][0];
#pragma unroll
    for (int rt = 0; rt < 4; ++rt)
#pragma unroll
      for (int i = 0; i < 4; ++i) mm = fmaxf(mm, acc[rt][ct][i]);
    m[ct] = mm;
  }
  // reduce across the 4 lanes sharing q (lane = g*16 + lc16)
#pragma unroll
  for (int ct = 0; ct < 4; ++ct) {
    m[ct] = fmaxf(m[ct], __shfl_xor(m[ct], 16));
    m[ct] = fmaxf(m[ct], __shfl_xor(m[ct], 32));
  }
  if (g == 0)
#pragma unroll
    for (int ct = 0; ct < 4; ++ct) redW[w][ct * 16 + lc16] = m[ct];
  __syncthreads();

  float thr[4];
#pragma unroll
  for (int ct = 0; ct < 4; ++ct) {
    const int qq = ct * 16 + lc16;
    thr[ct] = fmaxf(fmaxf(redW[0][qq], redW[1][qq]),
                    fmaxf(redW[2][qq], redW[3][qq])) - 1.0f;
  }

#pragma unroll
  for (int rt = 0; rt < 4; ++rt)
#pragma unroll
    for (int ct = 0; ct < 4; ++ct)
#pragma unroll
      for (int i = 0; i < 4; ++i) {
        const float v = acc[rt][ct][i];
        if (v > thr[ct]) {
          const int row = pair * TS + qb + ct * 16 + lc16;
          const int pos = atomicAdd(&cnt[row], 1);
          if (pos < capN) {
            idxL[(size_t)row * capN + pos] = (unsigned short)(jb + rt * 16 + g * 4 + i);
            valL[(size_t)row * capN + pos] = v;
          }
        }
      }
}

// ---------------------------------------------------------------------------
// spv: one block per (b,q); 8 heads' candidate lists -> exact rowmax =
// max(list) -> list-Michelot (wave w: heads 2w,2w+1) -> avg scatter into LDS
// row, one dense write -> sparse PV. Dense recompute fallback on overflow.
// ---------------------------------------------------------------------------
__global__ __launch_bounds__(256) void spv(
    const int* __restrict__ cnt, const unsigned short* __restrict__ idxL,
    const float* __restrict__ valL, int capN,
    const short* __restrict__ Qh, const short* __restrict__ Kh,
    const float* __restrict__ V,
    short* __restrict__ heads, float* __restrict__ avg)
{
  __shared__ float avgS[TS];          // 8 KB
  __shared__ float zdense[TS];        // 8 KB (fallback only)
  __shared__ float tauS[TH];
  __shared__ int   cntH[TH];
  __shared__ float redA[4], redB[4], redMx[4];
  __shared__ float qrowS[TDH];
  __shared__ float hp[4][TDH];

  const int tid  = threadIdx.x;
  const int w    = tid >> 6;
  const int lane = tid & 63;
  const int q    = blockIdx.x;
  const int bsel = blockIdx.y;
  const int row  = bsel * TS + q;

  if (tid < TH) cntH[tid] = cnt[(size_t)(bsel * TH + tid) * TS + q];
#pragma unroll
  for (int j = 0; j < 8; ++j) avgS[tid + (j << 8)] = 0.f;
  __syncthreads();

  const float* Vb = V + (size_t)bsel * TS * TDH;

  // ---- normal heads: wave w owns heads 2w, 2w+1 ----
#pragma unroll
  for (int hh = 0; hh < 2; ++hh) {
    const int h = w * 2 + hh;
    const int c = cntH[h];
    if (c <= capN) {
      const size_t rb = ((size_t)(bsel * TH + h) * TS + q) * capN;
      float cv[4];
      int ci[4];
#pragma unroll
      for (int e = 0; e < 4; ++e) {
        const int ii = lane + e * 64;
        const bool ok = ii < c;
        cv[e] = ok ? valL[rb + ii] : -1e30f;
        ci[e] = ok ? (int)idxL[rb + ii] : 0;
      }
      // exact row max = max over admitted values
      float gm = fmaxf(fmaxf(cv[0], cv[1]), fmaxf(cv[2], cv[3]));
#pragma unroll
      for (int m = 1; m < 64; m <<= 1) gm = fmaxf(gm, __shfl_xor(gm, m));
      float tau = gm - 1.0f;
      int prevc = -1;
      for (int it = 0; it < 64; ++it) {
        float s = 0.f, cc = 0.f;
#pragma unroll
        for (int e = 0; e < 4; ++e) {
          if (cv[e] > tau) { s += cv[e]; cc += 1.f; }
        }
#pragma unroll
        for (int m = 1; m < 64; m <<= 1) {
          s  += __shfl_xor(s, m);
          cc += __shfl_xor(cc, m);
        }
        tau = (s - 1.f) / cc;
        const int ci2 = (int)cc;
        if (ci2 == prevc) break;
        prevc = ci2;
      }
      if (lane == 0) tauS[h] = tau;
      // avg scatter (this wave's entries only)
#pragma unroll
      for (int e = 0; e < 4; ++e) {
        const int ii = lane + e * 64;
        const float p = cv[e] - tau;
        if (ii < c && p > 0.f) atomicAdd(&avgS[ci[e]], p * 0.125f);
      }
      // sparse PV: lane = dh, batched 8-wide
      float a = 0.f;
      for (int e0 = 0; e0 < c; e0 += 8) {
        float pb[8], vb8[8];
#pragma unroll
        for (int u = 0; u < 8; ++u) {
          const int e = e0 + u;
          const int ec = (e < c) ? e : 0;
          pb[u] = (e < c) ? (valL[rb + ec] - tau) : 0.f;
          vb8[u] = Vb[(size_t)idxL[rb + ec] * TDH + lane];
        }
#pragma unroll
        for (int u = 0; u < 8; ++u) a += fmaxf(pb[u], 0.f) * vb8[u];
      }
      heads[(size_t)row * TD + h * TDH + lane] = (short)f2bf(a);
    }
  }

  // ---- dense fallback for overflowed heads (rare) ----
  const int over = (tid < TH) ? (cntH[tid] > capN) : 0;
  if (__syncthreads_or(over)) {
    for (int h = 0; h < TH; ++h) {
      if (cntH[h] <= capN) continue;         // uniform branch
      const int pair = bsel * TH + h;
      if (tid < TDH)
        qrowS[tid] = bf2f((unsigned short)Qh[((size_t)pair * TS + q) * TDH + tid]);
      __syncthreads();
      const short* Kp = Kh + (size_t)pair * TS * TDH;
      for (int u = 0; u < 8; ++u) {
        const int j = tid * 8 + u;
        const short* kr = Kp + (size_t)j * TDH;
        float s = 0.f;
        for (int d = 0; d < TDH; ++d) s += qrowS[d] * bf2f((unsigned short)kr[d]);
        zdense[j] = s;
      }
      __syncthreads();
      float lmax = -1e30f;
#pragma unroll
      for (int jj = 0; jj < 8; ++jj) lmax = fmaxf(lmax, zdense[(jj << 8) + tid]);
      for (int off = 32; off; off >>= 1) lmax = fmaxf(lmax, __shfl_down(lmax, off));
      if (lane == 0) redMx[w] = lmax;
      __syncthreads();
      float tau = fmaxf(fmaxf(redMx[0], redMx[1]), fmaxf(redMx[2], redMx[3])) - 1.0f;
      int prevc = -1;
      for (int it = 0; it < 64; ++it) {
        float ls = 0.f, lc = 0.f;
#pragma unroll
        for (int jj = 0; jj < 8; ++jj) {
          const float v = zdense[(jj << 8) + tid];
          if (v > tau) { ls += v; lc += 1.f; }
        }
        for (int off = 32; off; off >>= 1) {
          ls += __shfl_down(ls, off);
          lc += __shfl_down(lc, off);
        }
        if (lane == 0) { redA[w] = ls; redB[w] = lc; }
        __syncthreads();
        const float ts = redA[0] + redA[1] + redA[2] + redA[3];
        const float tc = redB[0] + redB[1] + redB[2] + redB[3];
        tau = (ts - 1.f) / tc;
        const int ci2 = (int)tc;
        __syncthreads();
        if (ci2 == prevc) break;
        prevc = ci2;
      }
      // avg contribution (thread-exclusive j ownership -> plain add)
#pragma unroll
      for (int jj = 0; jj < 8; ++jj) {
        const int j = (jj << 8) + tid;
        const float p = zdense[j] - tau;
        if (p > 0.f) avgS[j] += p * 0.125f;
      }
      // dense PV
      float a = 0.f;
      for (int j = w * 512; j < w * 512 + 512; ++j) {
        const float p = zdense[j] - tau;
        if (p > 0.f) a += p * Vb[(size_t)j * TDH + lane];
      }
      hp[w][lane] = a;
      __syncthreads();
      if (w == 0)
        heads[(size_t)row * TD + h * TDH + lane] =
            (short)f2bf((hp[0][lane] + hp[1][lane]) + (hp[2][lane] + hp[3][lane]));
      __syncthreads();
    }
  }

  // ---- dense avg write (all heads' contributions in avgS) ----
  {
    float* ap = avg + (size_t)row * TS + (tid << 3);
    float4 o0 = {avgS[(tid << 3) + 0], avgS[(tid << 3) + 1],
                 avgS[(tid << 3) + 2], avgS[(tid << 3) + 3]};
    float4 o1 = {avgS[(tid << 3) + 4], avgS[(tid << 3) + 5],
                 avgS[(tid << 3) + 6], avgS[(tid << 3) + 7]};
    *(float4*)ap = o0;
    *(float4*)(ap + 4) = o1;
  }
}

// ---------------------------------------------------------------------------
extern "C" void kernel_launch(void* const* d_in, const int* in_sizes, int n_in,
                              void* d_out, int out_size, void* d_ws, size_t ws_size,
                              hipStream_t stream) {
  (void)in_sizes; (void)n_in; (void)out_size;

  const float* x    = (const float*)d_in[0];
  const float* Wq   = (const float*)d_in[1];
  const float* bq   = (const float*)d_in[2];
  const float* Wk   = (const float*)d_in[3];
  const float* bk   = (const float*)d_in[4];
  const float* Wv   = (const float*)d_in[5];
  const float* bv   = (const float*)d_in[6];
  const float* Wout = (const float*)d_in[7];
  const float* bout = (const float*)d_in[8];

  float* out   = (float*)d_out;
  float* x_out = out;                       // [2,2048,512]
  float* avg   = out + 2097152;             // [2,2048,2048]

  float* ws = (float*)d_ws;
  float* Vb = ws;                           // f32 [2][2048][64]   (262144 fl)
  short* Hd = (short*)(ws + 262144);        // bf16 [4096][512]    (1048576 fl)
  short* Qh = (short*)(ws + 1310720);       // bf16 [16][2048][64] (1048576 fl)
  short* Kh = (short*)(ws + 2359296);       // bf16 [16][2048][64] (1048576 fl)
  int*   cntL = (int*)(ws + 3407872);       // int [32768]         (32768 fl)
  float* valL = ws + 3440640;               // f32 [32768][capN]
  // idxL placed after valL once capN chosen

  // choose capN to fit workspace: lists need 32768*capN*(4+2) bytes
  const size_t wsFloats = ws_size / 4;
  const size_t base = 3440640;
  int capN = 64;
  for (int cand = 256; cand >= 64; cand >>= 1) {
    const size_t need = base + (size_t)32768 * cand + ((size_t)32768 * cand + 1) / 2;
    if (need <= wsFloats) { capN = cand; break; }
  }
  unsigned short* idxL = (unsigned short*)(valL + (size_t)32768 * capN);

  const dim3 blk(256);
  const int BS = 2 * TS;                    // 4096 rows

  // fused QKV projections (one launch)
  proj_gemm<<<dim3(BS / 64, 17), blk, 0, stream>>>(x, Wq, bq, Wk, bk, Wv, bv, Qh, Kh, Vb);

  // zero candidate counters
  hipMemsetAsync(cntL, 0, 32768 * sizeof(int), stream);

  // candidate emission (no Z materialization)
  zcand<<<dim3(TS / 256, TS / 64, 16), blk, 0, stream>>>(Qh, Kh, cntL, idxL, valL, capN);

  // sparsemax + avg + PV per (b,q)
  spv<<<dim3(TS, 2), blk, 0, stream>>>(cntL, idxL, valL, capN, Qh, Kh, Vb, Hd, avg);

  // output projection
  gemm_out<<<dim3(BS / 64, TD / 64), blk, 0, stream>>>(Hd, Wout, bout, x_out, TD, TD);
}

// Round 10
// 208.721 us; speedup vs baseline: 5.3646x; 5.3646x over previous
//
#include <hip/hip_runtime.h>
#include <cstddef>
#include <cstdint>

#define TS 2048   // sequence length S
#define TD 512    // model dim D
#define TH 8      // heads
#define TDH 64    // head dim
#define CAP 256   // support entries per head-row list (ballot fallback beyond)

typedef float f32x4 __attribute__((ext_vector_type(4)));
typedef short short8v __attribute__((ext_vector_type(8)));

__device__ __forceinline__ unsigned short f2bf(float f) {
  unsigned u = __builtin_bit_cast(unsigned, f);
  u += 0x7fff + ((u >> 16) & 1);          // RNE
  return (unsigned short)(u >> 16);
}

// ---------------------------------------------------------------------------
// Fused QKV projection (proven R9): one launch, W selected per blockIdx.y.
// by 0..7 -> Wq (bf16 head-major Qh), 8..15 -> Wk (-> Kh), 16 -> Wv (f32 Vb).
// ---------------------------------------------------------------------------
__global__ __launch_bounds__(256) void proj_gemm(
    const float* __restrict__ x,
    const float* __restrict__ Wq, const float* __restrict__ bq,
    const float* __restrict__ Wk, const float* __restrict__ bk,
    const float* __restrict__ Wv, const float* __restrict__ bv,
    short* __restrict__ Qh, short* __restrict__ Kh, float* __restrict__ Vb)
{
  __shared__ short As[64][40];
  __shared__ short Bs[64][40];

  const int by = blockIdx.y;
  const float* W; const float* bias; int N; int col0; int outsel;
  if (by < 8)       { W = Wq; bias = bq; N = TD;  col0 = by * 64;       outsel = 0; }
  else if (by < 16) { W = Wk; bias = bk; N = TD;  col0 = (by - 8) * 64; outsel = 1; }
  else              { W = Wv; bias = bv; N = TDH; col0 = 0;             outsel = 2; }

  const int tid  = threadIdx.x;
  const int w    = tid >> 6;
  const int lane = tid & 63;
  const int g    = lane >> 4;
  const int lc16 = lane & 15;
  const int wm   = w >> 1;
  const int wn   = w & 1;
  const int row0 = blockIdx.x * 64;

  const int ar = tid >> 2;
  const int ak = (tid & 3) << 3;
  const int wk = tid >> 3;
  const int wn8 = (tid & 7) << 3;

  f32x4 acc[2][2];
#pragma unroll
  for (int i = 0; i < 2; ++i)
#pragma unroll
    for (int j = 0; j < 2; ++j) acc[i][j] = (f32x4){0.f, 0.f, 0.f, 0.f};

  for (int kt = 0; kt < TD; kt += 32) {
    {
      const float* ap = x + (size_t)(row0 + ar) * TD + kt + ak;
      float4 f0 = *(const float4*)ap;
      float4 f1 = *(const float4*)(ap + 4);
      short8v v;
      v[0] = (short)f2bf(f0.x); v[1] = (short)f2bf(f0.y);
      v[2] = (short)f2bf(f0.z); v[3] = (short)f2bf(f0.w);
      v[4] = (short)f2bf(f1.x); v[5] = (short)f2bf(f1.y);
      v[6] = (short)f2bf(f1.z); v[7] = (short)f2bf(f1.w);
      *(short8v*)&As[ar][ak] = v;
    }
    {
      const float* wp = W + (size_t)(kt + wk) * N + col0 + wn8;
      float4 f0 = *(const float4*)wp;
      float4 f1 = *(const float4*)(wp + 4);
      Bs[wn8 + 0][wk] = (short)f2bf(f0.x);
      Bs[wn8 + 1][wk] = (short)f2bf(f0.y);
      Bs[wn8 + 2][wk] = (short)f2bf(f0.z);
      Bs[wn8 + 3][wk] = (short)f2bf(f0.w);
      Bs[wn8 + 4][wk] = (short)f2bf(f1.x);
      Bs[wn8 + 5][wk] = (short)f2bf(f1.y);
      Bs[wn8 + 6][wk] = (short)f2bf(f1.z);
      Bs[wn8 + 7][wk] = (short)f2bf(f1.w);
    }
    __syncthreads();

    short8v a0 = *(const short8v*)&As[wm * 32 + lc16][g * 8];
    short8v a1 = *(const short8v*)&As[wm * 32 + 16 + lc16][g * 8];
    short8v b0 = *(const short8v*)&Bs[wn * 32 + lc16][g * 8];
    short8v b1 = *(const short8v*)&Bs[wn * 32 + 16 + lc16][g * 8];
    acc[0][0] = __builtin_amdgcn_mfma_f32_16x16x32_bf16(a0, b0, acc[0][0], 0, 0, 0);
    acc[0][1] = __builtin_amdgcn_mfma_f32_16x16x32_bf16(a0, b1, acc[0][1], 0, 0, 0);
    acc[1][0] = __builtin_amdgcn_mfma_f32_16x16x32_bf16(a1, b0, acc[1][0], 0, 0, 0);
    acc[1][1] = __builtin_amdgcn_mfma_f32_16x16x32_bf16(a1, b1, acc[1][1], 0, 0, 0);
    __syncthreads();
  }

  short* Obf = (outsel == 0) ? Qh : Kh;
#pragma unroll
  for (int ni = 0; ni < 2; ++ni) {
    const int ocol = col0 + wn * 32 + ni * 16 + lc16;
    if (ocol >= N) continue;
    const float bb = bias[ocol];
#pragma unroll
    for (int mi = 0; mi < 2; ++mi)
#pragma unroll
      for (int r = 0; r < 4; ++r) {
        const int orow = row0 + wm * 32 + mi * 16 + g * 4 + r;
        const float val = acc[mi][ni][r] + bb;
        if (outsel == 2) {
          Vb[(size_t)orow * TDH + ocol] = val;
        } else {
          const int bI = orow >> 11, s = orow & 2047;
          const int hI = ocol >> 6, dh = ocol & 63;
          Obf[(((size_t)(bI * TH + hI) * TS + s) * TDH) + dh] = (short)f2bf(val);
        }
      }
  }
}

// ---------------------------------------------------------------------------
// Output projection GEMM (proven): x_out = Hd(bf16) @ Wout + bout.
// ---------------------------------------------------------------------------
__global__ __launch_bounds__(256) void gemm_out(
    const short* __restrict__ A, const float* __restrict__ W,
    const float* __restrict__ bias, float* __restrict__ Cf, int N, int Kd)
{
  __shared__ short As[64][40];
  __shared__ short Bs[64][40];

  const int tid  = threadIdx.x;
  const int w    = tid >> 6;
  const int lane = tid & 63;
  const int g    = lane >> 4;
  const int lc16 = lane & 15;
  const int wm   = w >> 1;
  const int wn   = w & 1;
  const int row0 = blockIdx.x * 64;
  const int col0 = blockIdx.y * 64;

  const int ar = tid >> 2;
  const int ak = (tid & 3) << 3;
  const int wk = tid >> 3;
  const int wn8 = (tid & 7) << 3;

  f32x4 acc[2][2];
#pragma unroll
  for (int i = 0; i < 2; ++i)
#pragma unroll
    for (int j = 0; j < 2; ++j) acc[i][j] = (f32x4){0.f, 0.f, 0.f, 0.f};

  for (int kt = 0; kt < Kd; kt += 32) {
    {
      short8v v = *(const short8v*)(A + (size_t)(row0 + ar) * Kd + kt + ak);
      *(short8v*)&As[ar][ak] = v;
    }
    {
      const float* wp = W + (size_t)(kt + wk) * N + col0 + wn8;
      float4 f0 = *(const float4*)wp;
      float4 f1 = *(const float4*)(wp + 4);
      Bs[wn8 + 0][wk] = (short)f2bf(f0.x);
      Bs[wn8 + 1][wk] = (short)f2bf(f0.y);
      Bs[wn8 + 2][wk] = (short)f2bf(f0.z);
      Bs[wn8 + 3][wk] = (short)f2bf(f0.w);
      Bs[wn8 + 4][wk] = (short)f2bf(f1.x);
      Bs[wn8 + 5][wk] = (short)f2bf(f1.y);
      Bs[wn8 + 6][wk] = (short)f2bf(f1.z);
      Bs[wn8 + 7][wk] = (short)f2bf(f1.w);
    }
    __syncthreads();

    short8v a0 = *(const short8v*)&As[wm * 32 + lc16][g * 8];
    short8v a1 = *(const short8v*)&As[wm * 32 + 16 + lc16][g * 8];
    short8v b0 = *(const short8v*)&Bs[wn * 32 + lc16][g * 8];
    short8v b1 = *(const short8v*)&Bs[wn * 32 + 16 + lc16][g * 8];
    acc[0][0] = __builtin_amdgcn_mfma_f32_16x16x32_bf16(a0, b0, acc[0][0], 0, 0, 0);
    acc[0][1] = __builtin_amdgcn_mfma_f32_16x16x32_bf16(a0, b1, acc[0][1], 0, 0, 0);
    acc[1][0] = __builtin_amdgcn_mfma_f32_16x16x32_bf16(a1, b0, acc[1][0], 0, 0, 0);
    acc[1][1] = __builtin_amdgcn_mfma_f32_16x16x32_bf16(a1, b1, acc[1][1], 0, 0, 0);
    __syncthreads();
  }

#pragma unroll
  for (int ni = 0; ni < 2; ++ni) {
    const int ocol = col0 + wn * 32 + ni * 16 + lc16;
    const float bb = bias[ocol];
#pragma unroll
    for (int mi = 0; mi < 2; ++mi)
#pragma unroll
      for (int r = 0; r < 4; ++r) {
        const int orow = row0 + wm * 32 + mi * 16 + g * 4 + r;
        Cf[(size_t)orow * N + ocol] = acc[mi][ni][r] + bb;
      }
  }
}

// ---------------------------------------------------------------------------
// zgemm (proven R8): Z[q][j] = Q.K^T, f32, slab rows. Register NT-GEMM,
// no LDS, no barriers. Block = 64q x 256j, one head. mfma(K,Q): D col = q,
// row = j -> lane's 4 acc values are 4 consecutive j -> float4 store.
// ---------------------------------------------------------------------------
__global__ __launch_bounds__(256) void zgemm(
    const short* __restrict__ Qh, const short* __restrict__ Kh,
    float* __restrict__ Zs, int bsel, int q0s, int qc)
{
  const int tid  = threadIdx.x;
  const int w    = tid >> 6;
  const int lane = tid & 63;
  const int g    = lane >> 4;
  const int lc16 = lane & 15;
  const int h    = blockIdx.z;
  const int pair = bsel * TH + h;
  const int jb   = blockIdx.x * 256 + w * 64;
  const int qlb  = blockIdx.y * 64;
  const int qb   = q0s + qlb;

  const short* Qp = Qh + (size_t)pair * TS * TDH;
  const short* Kp = Kh + (size_t)pair * TS * TDH;

  short8v bq[4][2];
#pragma unroll
  for (int ct = 0; ct < 4; ++ct) {
    const short* qp = Qp + (size_t)(qb + ct * 16 + lc16) * TDH + g * 8;
    bq[ct][0] = *(const short8v*)qp;
    bq[ct][1] = *(const short8v*)(qp + 32);
  }

  f32x4 acc[4][4];
#pragma unroll
  for (int rt = 0; rt < 4; ++rt)
#pragma unroll
    for (int ct = 0; ct < 4; ++ct) acc[rt][ct] = (f32x4){0.f, 0.f, 0.f, 0.f};

#pragma unroll
  for (int rt = 0; rt < 4; ++rt) {
    const short* kp = Kp + (size_t)(jb + rt * 16 + lc16) * TDH + g * 8;
    short8v ak0 = *(const short8v*)kp;
    short8v ak1 = *(const short8v*)(kp + 32);
#pragma unroll
    for (int ct = 0; ct < 4; ++ct) {
      acc[rt][ct] = __builtin_amdgcn_mfma_f32_16x16x32_bf16(ak0, bq[ct][0], acc[rt][ct], 0, 0, 0);
      acc[rt][ct] = __builtin_amdgcn_mfma_f32_16x16x32_bf16(ak1, bq[ct][1], acc[rt][ct], 0, 0, 0);
    }
  }

#pragma unroll
  for (int rt = 0; rt < 4; ++rt)
#pragma unroll
    for (int ct = 0; ct < 4; ++ct) {
      float4 o = {acc[rt][ct][0], acc[rt][ct][1], acc[rt][ct][2], acc[rt][ct][3]};
      *(float4*)&Zs[((size_t)h * qc + qlb + ct * 16 + lc16) * TS + jb + rt * 16 + g * 4] = o;
    }
}

// ---------------------------------------------------------------------------
// spv v2: one block per (b,q); wave w owns heads w and w+4 END-TO-END.
// Row (2048 f32) lives in 8 f32x4 registers per lane (j = k*256 + lane*4 + c).
// Wave-local: max -> dense in-register Michelot (exact tau, no barriers) ->
// support list (p>0) to LDS -> sparse PV gather -> heads write. avg
// accumulated in registers; cross-wave combine via 4 phased barriers; one
// dense coalesced write. Ballot-serial PV fallback if support > CAP (rare).
// ---------------------------------------------------------------------------
__global__ __launch_bounds__(256) void spv(
    const float* __restrict__ Zs, const float* __restrict__ V,
    short* __restrict__ heads, float* __restrict__ avg,
    int bsel, int q0s, int qc)
{
  __shared__ float avgS[TS];                 // 8 KB
  __shared__ unsigned short idxW[4][CAP];    // 2 KB
  __shared__ float pW[4][CAP];               // 4 KB
  __shared__ int cntW[4];

  const int tid  = threadIdx.x;
  const int w    = tid >> 6;
  const int lane = tid & 63;
  const int ql   = blockIdx.x;
  const int q    = q0s + ql;
  const int row  = bsel * TS + q;
  const float* Vb = V + (size_t)bsel * TS * TDH;

  f32x4 av[8];
#pragma unroll
  for (int k = 0; k < 8; ++k) av[k] = (f32x4){0.f, 0.f, 0.f, 0.f};

  for (int hh = 0; hh < 2; ++hh) {
    const int h = w + hh * 4;

    // ---- load row into registers: j = k*256 + lane*4 + c ----
    f32x4 za[8];
    const float* zp = Zs + ((size_t)h * qc + ql) * TS;
#pragma unroll
    for (int k = 0; k < 8; ++k) za[k] = *(const f32x4*)(zp + k * 256 + lane * 4);

    // ---- wave row max ----
    float m = za[0][0];
#pragma unroll
    for (int k = 0; k < 8; ++k)
#pragma unroll
      for (int c = 0; c < 4; ++c) m = fmaxf(m, za[k][c]);
#pragma unroll
    for (int s = 1; s < 64; s <<= 1) m = fmaxf(m, __shfl_xor(m, s));

    // ---- dense in-register Michelot (exact tau, wave-local) ----
    float tau = m - 1.0f;
    int prevc = -1;
    for (int it = 0; it < 64; ++it) {
      float s = 0.f, c = 0.f;
#pragma unroll
      for (int k = 0; k < 8; ++k)
#pragma unroll
        for (int cc = 0; cc < 4; ++cc) {
          const float v = za[k][cc];
          if (v > tau) { s += v; c += 1.f; }
        }
#pragma unroll
      for (int sh = 1; sh < 64; sh <<= 1) {
        s += __shfl_xor(s, sh);
        c += __shfl_xor(c, sh);
      }
      tau = (s - 1.f) / c;
      const int ci = (int)c;
      if (ci == prevc) break;
      prevc = ci;
    }

    // ---- avg accumulation (dense, in registers) ----
#pragma unroll
    for (int k = 0; k < 8; ++k)
#pragma unroll
      for (int c = 0; c < 4; ++c) av[k][c] += fmaxf(za[k][c] - tau, 0.f);

    // ---- support list (p > 0) into wave-local LDS ----
    if (lane == 0) cntW[w] = 0;
#pragma unroll
    for (int k = 0; k < 8; ++k)
#pragma unroll
      for (int c = 0; c < 4; ++c) {
        const float p = za[k][c] - tau;
        if (p > 0.f) {
          const int pos = atomicAdd(&cntW[w], 1);
          if (pos < CAP) {
            idxW[w][pos] = (unsigned short)((k << 8) + (lane << 2) + c);
            pW[w][pos] = p;
          }
        }
      }
    const int cnt = cntW[w];        // wave-local: all atomics program-ordered

    // ---- PV ----
    float a = 0.f;
    if (cnt <= CAP) {
      for (int e0 = 0; e0 < cnt; e0 += 8) {
        float pb[8], vb8[8];
#pragma unroll
        for (int u = 0; u < 8; ++u) {
          const int e = e0 + u;
          const int ec = (e < cnt) ? e : 0;
          pb[u] = (e < cnt) ? pW[w][ec] : 0.f;
          vb8[u] = Vb[(size_t)idxW[w][ec] * TDH + lane];
        }
#pragma unroll
        for (int u = 0; u < 8; ++u) a += pb[u] * vb8[u];
      }
    } else {
      // ballot-serial dense fallback (support > CAP; rare)
#pragma unroll
      for (int k = 0; k < 8; ++k)
#pragma unroll
        for (int c = 0; c < 4; ++c) {
          const float p = za[k][c] - tau;
          unsigned long long mask = __ballot(p > 0.f);
          while (mask) {
            const int src = __ffsll((long long)mask) - 1;
            mask &= mask - 1;
            const float pj = __shfl(p, src);
            const int j = (k << 8) + (src << 2) + c;
            a += pj * Vb[(size_t)j * TDH + lane];
          }
        }
    }
    heads[(size_t)row * TD + h * TDH + lane] = (short)f2bf(a);
  }

  // ---- cross-wave avg combine (phased, 4 barriers) then dense write ----
  if (w == 0)
#pragma unroll
    for (int k = 0; k < 8; ++k)
      *(f32x4*)&avgS[(k << 8) + (lane << 2)] = av[k] * 0.125f;
  __syncthreads();
  if (w == 1)
#pragma unroll
    for (int k = 0; k < 8; ++k) {
      f32x4 t = *(f32x4*)&avgS[(k << 8) + (lane << 2)];
      *(f32x4*)&avgS[(k << 8) + (lane << 2)] = t + av[k] * 0.125f;
    }
  __syncthreads();
  if (w == 2)
#pragma unroll
    for (int k = 0; k < 8; ++k) {
      f32x4 t = *(f32x4*)&avgS[(k << 8) + (lane << 2)];
      *(f32x4*)&avgS[(k << 8) + (lane << 2)] = t + av[k] * 0.125f;
    }
  __syncthreads();
  if (w == 3)
#pragma unroll
    for (int k = 0; k < 8; ++k) {
      f32x4 t = *(f32x4*)&avgS[(k << 8) + (lane << 2)];
      *(f32x4*)&avgS[(k << 8) + (lane << 2)] = t + av[k] * 0.125f;
    }
  __syncthreads();

  {
    float* ap = avg + (size_t)row * TS + (tid << 3);
    float4 o0 = {avgS[(tid << 3) + 0], avgS[(tid << 3) + 1],
                 avgS[(tid << 3) + 2], avgS[(tid << 3) + 3]};
    float4 o1 = {avgS[(tid << 3) + 4], avgS[(tid << 3) + 5],
                 avgS[(tid << 3) + 6], avgS[(tid << 3) + 7]};
    *(float4*)ap = o0;
    *(float4*)(ap + 4) = o1;
  }
}

// ---------------------------------------------------------------------------
extern "C" void kernel_launch(void* const* d_in, const int* in_sizes, int n_in,
                              void* d_out, int out_size, void* d_ws, size_t ws_size,
                              hipStream_t stream) {
  (void)in_sizes; (void)n_in; (void)out_size;

  const float* x    = (const float*)d_in[0];
  const float* Wq   = (const float*)d_in[1];
  const float* bq   = (const float*)d_in[2];
  const float* Wk   = (const float*)d_in[3];
  const float* bk   = (const float*)d_in[4];
  const float* Wv   = (const float*)d_in[5];
  const float* bv   = (const float*)d_in[6];
  const float* Wout = (const float*)d_in[7];
  const float* bout = (const float*)d_in[8];

  float* out   = (float*)d_out;
  float* x_out = out;                       // [2,2048,512]
  float* avg   = out + 2097152;             // [2,2048,2048]

  float* ws = (float*)d_ws;
  float* Vb = ws;                           // f32 [2][2048][64]   (262144 fl)
  short* Hd = (short*)(ws + 262144);        // bf16 [4096][512]    (1048576 fl)
  short* Qh = (short*)(ws + 1310720);       // bf16 [16][2048][64] (1048576 fl)
  short* Kh = (short*)(ws + 2359296);       // bf16 [16][2048][64] (1048576 fl)
  float* Zs = ws + 3407872;                 // f32 slab [8][qc][2048]

  // largest q-chunk that fits the workspace
  const size_t wsFloats = ws_size / 4;
  const size_t base = 3407872;
  int qc = 64;
  for (int cand = 2048; cand >= 64; cand >>= 1) {
    if (base + (size_t)TH * cand * TS <= wsFloats) { qc = cand; break; }
  }

  const dim3 blk(256);
  const int BS = 2 * TS;                    // 4096 rows

  // fused QKV projections
  proj_gemm<<<dim3(BS / 64, 17), blk, 0, stream>>>(x, Wq, bq, Wk, bk, Wv, bv, Qh, Kh, Vb);

  // attention, slabbed over (batch, q-chunk)
  for (int bsel = 0; bsel < 2; ++bsel)
    for (int q0s = 0; q0s < TS; q0s += qc) {
      zgemm<<<dim3(TS / 256, qc / 64, TH), blk, 0, stream>>>(Qh, Kh, Zs, bsel, q0s, qc);
      spv<<<dim3(qc), blk, 0, stream>>>(Zs, Vb, Hd, avg, bsel, q0s, qc);
    }

  // output projection
  gemm_out<<<dim3(BS / 64, TD / 64), blk, 0, stream>>>(Hd, Wout, bout, x_out, TD, TD);
}

// Round 11
// 174.765 us; speedup vs baseline: 6.4069x; 1.1943x over previous
//
#include <hip/hip_runtime.h>
#include <cstddef>
#include <cstdint>

#define TS 2048   // sequence length S
#define TD 512    // model dim D
#define TH 8      // heads
#define TDH 64    // head dim
#define CAP 256   // support entries per head list (ballot fallback beyond)

typedef float f32x4 __attribute__((ext_vector_type(4)));
typedef short short8v __attribute__((ext_vector_type(8)));

__device__ __forceinline__ unsigned short f2bf(float f) {
  unsigned u = __builtin_bit_cast(unsigned, f);
  u += 0x7fff + ((u >> 16) & 1);          // RNE
  return (unsigned short)(u >> 16);
}

// ---------------------------------------------------------------------------
// Fused QKV projection (proven R9/R10): one launch, W selected per blockIdx.y.
// by 0..7 -> Wq (bf16 head-major Qh), 8..15 -> Wk (-> Kh), 16 -> Wv (f32 Vb).
// ---------------------------------------------------------------------------
__global__ __launch_bounds__(256) void proj_gemm(
    const float* __restrict__ x,
    const float* __restrict__ Wq, const float* __restrict__ bq,
    const float* __restrict__ Wk, const float* __restrict__ bk,
    const float* __restrict__ Wv, const float* __restrict__ bv,
    short* __restrict__ Qh, short* __restrict__ Kh, float* __restrict__ Vb)
{
  __shared__ short As[64][40];
  __shared__ short Bs[64][40];

  const int by = blockIdx.y;
  const float* W; const float* bias; int N; int col0; int outsel;
  if (by < 8)       { W = Wq; bias = bq; N = TD;  col0 = by * 64;       outsel = 0; }
  else if (by < 16) { W = Wk; bias = bk; N = TD;  col0 = (by - 8) * 64; outsel = 1; }
  else              { W = Wv; bias = bv; N = TDH; col0 = 0;             outsel = 2; }

  const int tid  = threadIdx.x;
  const int w    = tid >> 6;
  const int lane = tid & 63;
  const int g    = lane >> 4;
  const int lc16 = lane & 15;
  const int wm   = w >> 1;
  const int wn   = w & 1;
  const int row0 = blockIdx.x * 64;

  const int ar = tid >> 2;
  const int ak = (tid & 3) << 3;
  const int wk = tid >> 3;
  const int wn8 = (tid & 7) << 3;

  f32x4 acc[2][2];
#pragma unroll
  for (int i = 0; i < 2; ++i)
#pragma unroll
    for (int j = 0; j < 2; ++j) acc[i][j] = (f32x4){0.f, 0.f, 0.f, 0.f};

  for (int kt = 0; kt < TD; kt += 32) {
    {
      const float* ap = x + (size_t)(row0 + ar) * TD + kt + ak;
      float4 f0 = *(const float4*)ap;
      float4 f1 = *(const float4*)(ap + 4);
      short8v v;
      v[0] = (short)f2bf(f0.x); v[1] = (short)f2bf(f0.y);
      v[2] = (short)f2bf(f0.z); v[3] = (short)f2bf(f0.w);
      v[4] = (short)f2bf(f1.x); v[5] = (short)f2bf(f1.y);
      v[6] = (short)f2bf(f1.z); v[7] = (short)f2bf(f1.w);
      *(short8v*)&As[ar][ak] = v;
    }
    {
      const float* wp = W + (size_t)(kt + wk) * N + col0 + wn8;
      float4 f0 = *(const float4*)wp;
      float4 f1 = *(const float4*)(wp + 4);
      Bs[wn8 + 0][wk] = (short)f2bf(f0.x);
      Bs[wn8 + 1][wk] = (short)f2bf(f0.y);
      Bs[wn8 + 2][wk] = (short)f2bf(f0.z);
      Bs[wn8 + 3][wk] = (short)f2bf(f0.w);
      Bs[wn8 + 4][wk] = (short)f2bf(f1.x);
      Bs[wn8 + 5][wk] = (short)f2bf(f1.y);
      Bs[wn8 + 6][wk] = (short)f2bf(f1.z);
      Bs[wn8 + 7][wk] = (short)f2bf(f1.w);
    }
    __syncthreads();

    short8v a0 = *(const short8v*)&As[wm * 32 + lc16][g * 8];
    short8v a1 = *(const short8v*)&As[wm * 32 + 16 + lc16][g * 8];
    short8v b0 = *(const short8v*)&Bs[wn * 32 + lc16][g * 8];
    short8v b1 = *(const short8v*)&Bs[wn * 32 + 16 + lc16][g * 8];
    acc[0][0] = __builtin_amdgcn_mfma_f32_16x16x32_bf16(a0, b0, acc[0][0], 0, 0, 0);
    acc[0][1] = __builtin_amdgcn_mfma_f32_16x16x32_bf16(a0, b1, acc[0][1], 0, 0, 0);
    acc[1][0] = __builtin_amdgcn_mfma_f32_16x16x32_bf16(a1, b0, acc[1][0], 0, 0, 0);
    acc[1][1] = __builtin_amdgcn_mfma_f32_16x16x32_bf16(a1, b1, acc[1][1], 0, 0, 0);
    __syncthreads();
  }

  short* Obf = (outsel == 0) ? Qh : Kh;
#pragma unroll
  for (int ni = 0; ni < 2; ++ni) {
    const int ocol = col0 + wn * 32 + ni * 16 + lc16;
    if (ocol >= N) continue;
    const float bb = bias[ocol];
#pragma unroll
    for (int mi = 0; mi < 2; ++mi)
#pragma unroll
      for (int r = 0; r < 4; ++r) {
        const int orow = row0 + wm * 32 + mi * 16 + g * 4 + r;
        const float val = acc[mi][ni][r] + bb;
        if (outsel == 2) {
          Vb[(size_t)orow * TDH + ocol] = val;
        } else {
          const int bI = orow >> 11, s = orow & 2047;
          const int hI = ocol >> 6, dh = ocol & 63;
          Obf[(((size_t)(bI * TH + hI) * TS + s) * TDH) + dh] = (short)f2bf(val);
        }
      }
  }
}

// ---------------------------------------------------------------------------
// Output projection GEMM (proven): x_out = Hd(bf16) @ Wout + bout.
// ---------------------------------------------------------------------------
__global__ __launch_bounds__(256) void gemm_out(
    const short* __restrict__ A, const float* __restrict__ W,
    const float* __restrict__ bias, float* __restrict__ Cf, int N, int Kd)
{
  __shared__ short As[64][40];
  __shared__ short Bs[64][40];

  const int tid  = threadIdx.x;
  const int w    = tid >> 6;
  const int lane = tid & 63;
  const int g    = lane >> 4;
  const int lc16 = lane & 15;
  const int wm   = w >> 1;
  const int wn   = w & 1;
  const int row0 = blockIdx.x * 64;
  const int col0 = blockIdx.y * 64;

  const int ar = tid >> 2;
  const int ak = (tid & 3) << 3;
  const int wk = tid >> 3;
  const int wn8 = (tid & 7) << 3;

  f32x4 acc[2][2];
#pragma unroll
  for (int i = 0; i < 2; ++i)
#pragma unroll
    for (int j = 0; j < 2; ++j) acc[i][j] = (f32x4){0.f, 0.f, 0.f, 0.f};

  for (int kt = 0; kt < Kd; kt += 32) {
    {
      short8v v = *(const short8v*)(A + (size_t)(row0 + ar) * Kd + kt + ak);
      *(short8v*)&As[ar][ak] = v;
    }
    {
      const float* wp = W + (size_t)(kt + wk) * N + col0 + wn8;
      float4 f0 = *(const float4*)wp;
      float4 f1 = *(const float4*)(wp + 4);
      Bs[wn8 + 0][wk] = (short)f2bf(f0.x);
      Bs[wn8 + 1][wk] = (short)f2bf(f0.y);
      Bs[wn8 + 2][wk] = (short)f2bf(f0.z);
      Bs[wn8 + 3][wk] = (short)f2bf(f0.w);
      Bs[wn8 + 4][wk] = (short)f2bf(f1.x);
      Bs[wn8 + 5][wk] = (short)f2bf(f1.y);
      Bs[wn8 + 6][wk] = (short)f2bf(f1.z);
      Bs[wn8 + 7][wk] = (short)f2bf(f1.w);
    }
    __syncthreads();

    short8v a0 = *(const short8v*)&As[wm * 32 + lc16][g * 8];
    short8v a1 = *(const short8v*)&As[wm * 32 + 16 + lc16][g * 8];
    short8v b0 = *(const short8v*)&Bs[wn * 32 + lc16][g * 8];
    short8v b1 = *(const short8v*)&Bs[wn * 32 + 16 + lc16][g * 8];
    acc[0][0] = __builtin_amdgcn_mfma_f32_16x16x32_bf16(a0, b0, acc[0][0], 0, 0, 0);
    acc[0][1] = __builtin_amdgcn_mfma_f32_16x16x32_bf16(a0, b1, acc[0][1], 0, 0, 0);
    acc[1][0] = __builtin_amdgcn_mfma_f32_16x16x32_bf16(a1, b0, acc[1][0], 0, 0, 0);
    acc[1][1] = __builtin_amdgcn_mfma_f32_16x16x32_bf16(a1, b1, acc[1][1], 0, 0, 0);
    __syncthreads();
  }

#pragma unroll
  for (int ni = 0; ni < 2; ++ni) {
    const int ocol = col0 + wn * 32 + ni * 16 + lc16;
    const float bb = bias[ocol];
#pragma unroll
    for (int mi = 0; mi < 2; ++mi)
#pragma unroll
      for (int r = 0; r < 4; ++r) {
        const int orow = row0 + wm * 32 + mi * 16 + g * 4 + r;
        Cf[(size_t)orow * N + ocol] = acc[mi][ni][r] + bb;
      }
  }
}

// ---------------------------------------------------------------------------
// zgemm (proven R8/R10): Z[q][j] = Q.K^T, f32, slab rows. Register NT-GEMM,
// no LDS, no barriers. Block = 64q x 256j, one head. mfma(K,Q): D col = q,
// row = j -> lane's 4 acc values are 4 consecutive j -> float4 store.
// ---------------------------------------------------------------------------
__global__ __launch_bounds__(256) void zgemm(
    const short* __restrict__ Qh, const short* __restrict__ Kh,
    float* __restrict__ Zs, int bsel, int q0s, int qc)
{
  const int tid  = threadIdx.x;
  const int w    = tid >> 6;
  const int lane = tid & 63;
  const int g    = lane >> 4;
  const int lc16 = lane & 15;
  const int h    = blockIdx.z;
  const int pair = bsel * TH + h;
  const int jb   = blockIdx.x * 256 + w * 64;
  const int qlb  = blockIdx.y * 64;
  const int qb   = q0s + qlb;

  const short* Qp = Qh + (size_t)pair * TS * TDH;
  const short* Kp = Kh + (size_t)pair * TS * TDH;

  short8v bq[4][2];
#pragma unroll
  for (int ct = 0; ct < 4; ++ct) {
    const short* qp = Qp + (size_t)(qb + ct * 16 + lc16) * TDH + g * 8;
    bq[ct][0] = *(const short8v*)qp;
    bq[ct][1] = *(const short8v*)(qp + 32);
  }

  f32x4 acc[4][4];
#pragma unroll
  for (int rt = 0; rt < 4; ++rt)
#pragma unroll
    for (int ct = 0; ct < 4; ++ct) acc[rt][ct] = (f32x4){0.f, 0.f, 0.f, 0.f};

#pragma unroll
  for (int rt = 0; rt < 4; ++rt) {
    const short* kp = Kp + (size_t)(jb + rt * 16 + lc16) * TDH + g * 8;
    short8v ak0 = *(const short8v*)kp;
    short8v ak1 = *(const short8v*)(kp + 32);
#pragma unroll
    for (int ct = 0; ct < 4; ++ct) {
      acc[rt][ct] = __builtin_amdgcn_mfma_f32_16x16x32_bf16(ak0, bq[ct][0], acc[rt][ct], 0, 0, 0);
      acc[rt][ct] = __builtin_amdgcn_mfma_f32_16x16x32_bf16(ak1, bq[ct][1], acc[rt][ct], 0, 0, 0);
    }
  }

#pragma unroll
  for (int rt = 0; rt < 4; ++rt)
#pragma unroll
    for (int ct = 0; ct < 4; ++ct) {
      float4 o = {acc[rt][ct][0], acc[rt][ct][1], acc[rt][ct][2], acc[rt][ct][3]};
      *(float4*)&Zs[((size_t)h * qc + qlb + ct * 16 + lc16) * TS + jb + rt * 16 + g * 4] = o;
    }
}

// ---------------------------------------------------------------------------
// spv v3: one block per (b,q), 512 threads = 8 waves, wave = one head.
// Row in 8 f32x4 regs (j = k*256 + lane*4 + c). Max scan -> tau0 = zmax-1 ->
// extract <=4 candidates/lane into NAMED regs (shift-register, static idx) ->
// 4-reg Michelot (exact; dense za fallback if any lane >4 cands) -> support
// scatter to zeroed LDS avg row + PV list -> batched sparse PV (ballot-serial
// dense fallback if support > CAP) -> heads write; one dense avg write.
// ---------------------------------------------------------------------------
__global__ __launch_bounds__(512) void spv(
    const float* __restrict__ Zs, const float* __restrict__ V,
    short* __restrict__ heads, float* __restrict__ avg,
    int bsel, int q0s, int qc)
{
  __shared__ float avgS[TS];                 // 8 KB
  __shared__ unsigned short idxW[TH][CAP];   // 4 KB
  __shared__ float pW[TH][CAP];              // 8 KB
  __shared__ int cntW[TH];

  const int tid  = threadIdx.x;
  const int h    = tid >> 6;                 // wave = head
  const int lane = tid & 63;
  const int ql   = blockIdx.x;
  const int q    = q0s + ql;
  const int row  = bsel * TS + q;
  const float* Vb = V + (size_t)bsel * TS * TDH;

  *(f32x4*)&avgS[tid << 2] = (f32x4){0.f, 0.f, 0.f, 0.f};
  if (lane == 0) cntW[h] = 0;
  __syncthreads();

  // ---- load row into registers ----
  f32x4 za[8];
  const float* zp = Zs + ((size_t)h * qc + ql) * TS;
#pragma unroll
  for (int k = 0; k < 8; ++k) za[k] = *(const f32x4*)(zp + (k << 8) + (lane << 2));

  // ---- wave row max ----
  float m = za[0][0];
#pragma unroll
  for (int k = 0; k < 8; ++k)
#pragma unroll
    for (int c = 0; c < 4; ++c) m = fmaxf(m, za[k][c]);
#pragma unroll
  for (int s = 1; s < 64; s <<= 1) m = fmaxf(m, __shfl_xor(m, s));
  const float tau0 = m - 1.0f;

  // ---- extract <=4 candidates per lane (named regs, static indexing) ----
  float c0 = -1e30f, c1 = -1e30f, c2 = -1e30f, c3 = -1e30f;
  int j0 = 0, j1 = 0, j2 = 0, j3 = 0, nc = 0;
#pragma unroll
  for (int k = 0; k < 8; ++k)
#pragma unroll
    for (int c = 0; c < 4; ++c) {
      const float v = za[k][c];
      if (v > tau0) {
        c3 = c2; j3 = j2; c2 = c1; j2 = j1; c1 = c0; j1 = j0;
        c0 = v; j0 = (k << 8) + (lane << 2) + c; ++nc;
      }
    }
  const bool over = (__ballot(nc > 4) != 0ull);

  // ---- Michelot fixpoint (exact tau) ----
  float tau = tau0;
  int prevc = -1;
  if (!over) {
    for (int it = 0; it < 64; ++it) {
      float s = 0.f, c = 0.f;
      if (c0 > tau) { s += c0; c += 1.f; }
      if (c1 > tau) { s += c1; c += 1.f; }
      if (c2 > tau) { s += c2; c += 1.f; }
      if (c3 > tau) { s += c3; c += 1.f; }
#pragma unroll
      for (int sh = 1; sh < 64; sh <<= 1) {
        s += __shfl_xor(s, sh);
        c += __shfl_xor(c, sh);
      }
      tau = (s - 1.f) / c;
      const int ci = (int)c;
      if (ci == prevc) break;
      prevc = ci;
    }
  } else {
    for (int it = 0; it < 64; ++it) {
      float s = 0.f, c = 0.f;
#pragma unroll
      for (int k = 0; k < 8; ++k)
#pragma unroll
        for (int cc = 0; cc < 4; ++cc) {
          const float v = za[k][cc];
          if (v > tau) { s += v; c += 1.f; }
        }
#pragma unroll
      for (int sh = 1; sh < 64; sh <<= 1) {
        s += __shfl_xor(s, sh);
        c += __shfl_xor(c, sh);
      }
      tau = (s - 1.f) / c;
      const int ci = (int)c;
      if (ci == prevc) break;
      prevc = ci;
    }
  }

  // ---- emit support: avg scatter + PV list ----
  if (!over) {
    {
      const float p = c0 - tau;
      if (p > 0.f) {
        atomicAdd(&avgS[j0], p);
        const int pos = atomicAdd(&cntW[h], 1);
        if (pos < CAP) { idxW[h][pos] = (unsigned short)j0; pW[h][pos] = p; }
      }
    }
    {
      const float p = c1 - tau;
      if (p > 0.f) {
        atomicAdd(&avgS[j1], p);
        const int pos = atomicAdd(&cntW[h], 1);
        if (pos < CAP) { idxW[h][pos] = (unsigned short)j1; pW[h][pos] = p; }
      }
    }
    {
      const float p = c2 - tau;
      if (p > 0.f) {
        atomicAdd(&avgS[j2], p);
        const int pos = atomicAdd(&cntW[h], 1);
        if (pos < CAP) { idxW[h][pos] = (unsigned short)j2; pW[h][pos] = p; }
      }
    }
    {
      const float p = c3 - tau;
      if (p > 0.f) {
        atomicAdd(&avgS[j3], p);
        const int pos = atomicAdd(&cntW[h], 1);
        if (pos < CAP) { idxW[h][pos] = (unsigned short)j3; pW[h][pos] = p; }
      }
    }
  } else {
#pragma unroll
    for (int k = 0; k < 8; ++k)
#pragma unroll
      for (int cc = 0; cc < 4; ++cc) {
        const float p = za[k][cc] - tau;
        if (p > 0.f) {
          const int j = (k << 8) + (lane << 2) + cc;
          atomicAdd(&avgS[j], p);
          const int pos = atomicAdd(&cntW[h], 1);
          if (pos < CAP) { idxW[h][pos] = (unsigned short)j; pW[h][pos] = p; }
        }
      }
  }

  // ---- PV (wave-local list; cnt visible: same-wave program order) ----
  const int cnt = cntW[h];
  float a = 0.f;
  if (cnt <= CAP) {
    for (int e0 = 0; e0 < cnt; e0 += 8) {
      float pb[8], vb8[8];
#pragma unroll
      for (int u = 0; u < 8; ++u) {
        const int e = e0 + u;
        const int ec = (e < cnt) ? e : 0;
        pb[u] = (e < cnt) ? pW[h][ec] : 0.f;
        vb8[u] = Vb[(size_t)idxW[h][ec] * TDH + lane];
      }
#pragma unroll
      for (int u = 0; u < 8; ++u) a += pb[u] * vb8[u];
    }
  } else {
    // ballot-serial dense fallback (support > CAP; essentially never)
#pragma unroll
    for (int k = 0; k < 8; ++k)
#pragma unroll
      for (int cc = 0; cc < 4; ++cc) {
        const float p = za[k][cc] - tau;
        unsigned long long mask = __ballot(p > 0.f);
        while (mask) {
          const int src = __ffsll((long long)mask) - 1;
          mask &= mask - 1;
          const float pj = __shfl(p, src);
          const int j = (k << 8) + (src << 2) + cc;
          a += pj * Vb[(size_t)j * TDH + lane];
        }
      }
  }
  heads[(size_t)row * TD + h * TDH + lane] = (short)f2bf(a);

  // ---- dense avg write ----
  __syncthreads();
  {
    f32x4 t = *(const f32x4*)&avgS[tid << 2];
    float4 o = {t[0] * 0.125f, t[1] * 0.125f, t[2] * 0.125f, t[3] * 0.125f};
    *(float4*)(avg + (size_t)row * TS + (tid << 2)) = o;
  }
}

// ---------------------------------------------------------------------------
extern "C" void kernel_launch(void* const* d_in, const int* in_sizes, int n_in,
                              void* d_out, int out_size, void* d_ws, size_t ws_size,
                              hipStream_t stream) {
  (void)in_sizes; (void)n_in; (void)out_size;

  const float* x    = (const float*)d_in[0];
  const float* Wq   = (const float*)d_in[1];
  const float* bq   = (const float*)d_in[2];
  const float* Wk   = (const float*)d_in[3];
  const float* bk   = (const float*)d_in[4];
  const float* Wv   = (const float*)d_in[5];
  const float* bv   = (const float*)d_in[6];
  const float* Wout = (const float*)d_in[7];
  const float* bout = (const float*)d_in[8];

  float* out   = (float*)d_out;
  float* x_out = out;                       // [2,2048,512]
  float* avg   = out + 2097152;             // [2,2048,2048]

  float* ws = (float*)d_ws;
  float* Vb = ws;                           // f32 [2][2048][64]   (262144 fl)
  short* Hd = (short*)(ws + 262144);        // bf16 [4096][512]    (1048576 fl)
  short* Qh = (short*)(ws + 1310720);       // bf16 [16][2048][64] (1048576 fl)
  short* Kh = (short*)(ws + 2359296);       // bf16 [16][2048][64] (1048576 fl)
  float* Zs = ws + 3407872;                 // f32 slab [8][qc][2048]

  // largest q-chunk that fits the workspace
  const size_t wsFloats = ws_size / 4;
  const size_t base = 3407872;
  int qc = 64;
  for (int cand = 2048; cand >= 64; cand >>= 1) {
    if (base + (size_t)TH * cand * TS <= wsFloats) { qc = cand; break; }
  }

  const dim3 blk(256);
  const int BS = 2 * TS;                    // 4096 rows

  // fused QKV projections
  proj_gemm<<<dim3(BS / 64, 17), blk, 0, stream>>>(x, Wq, bq, Wk, bk, Wv, bv, Qh, Kh, Vb);

  // attention, slabbed over (batch, q-chunk)
  for (int bsel = 0; bsel < 2; ++bsel)
    for (int q0s = 0; q0s < TS; q0s += qc) {
      zgemm<<<dim3(TS / 256, qc / 64, TH), blk, 0, stream>>>(Qh, Kh, Zs, bsel, q0s, qc);
      spv<<<dim3(qc), dim3(512), 0, stream>>>(Zs, Vb, Hd, avg, bsel, q0s, qc);
    }

  // output projection
  gemm_out<<<dim3(BS / 64, TD / 64), blk, 0, stream>>>(Hd, Wout, bout, x_out, TD, TD);
}